// Round 16
// baseline (266.490 us; speedup 1.0000x reference)
//
#include <hip/hip_runtime.h>

// ---------------------------------------------------------------------------
// HabitatGNN: 2-layer GCN (self loops, symmetric norm) + linear head.
// x:[N,128] f32, edge_index:[2,E] int32, W1:[128,64], W2:[64,32], Wc:[32,1].
//
// R5:  atomic scatter = 75% of runtime -> CSR + gather.
// R6:  single-block scan = 51% -> 3-phase device-wide scan.
// R7-R13: gemm 70->~44 (micro-tile + transposed Xs).
// R14: dinv folded into gemm epilogue + agg 4-way unroll: agg -10us (kept).
//      gemm prefetch depth-2: REGRESSED 39.6->49 (reverted).
// R16: gemm barrier/occupancy fix: (a) single barrier per k-tile (write next
//      tile into the buffer nobody reads this iter); (b) layer-1 OUT split
//      across 2 blocks -> Ws 16KB, LDS 49.8KB, 3 blocks/CU (12 waves),
//      1564 blocks; (c) prefetch depth 1.
// ---------------------------------------------------------------------------

#define SCAN_THREADS 256
#define SCAN_PER_T   8
#define SCAN_TILE    (SCAN_THREADS * SCAN_PER_T)   // 2048 elements per block

__global__ __launch_bounds__(256) void count_kernel(const int* __restrict__ dst,
                                                    int* __restrict__ deg, int E) {
    int e = blockIdx.x * blockDim.x + threadIdx.x;
    if (e < E) atomicAdd(&deg[dst[e]], 1);
}

__global__ __launch_bounds__(SCAN_THREADS) void tile_reduce_kernel(const int* __restrict__ deg,
                                                                   int* __restrict__ bsum,
                                                                   int n) {
    __shared__ int s[SCAN_THREADS];
    int t = threadIdx.x;
    int gbase = blockIdx.x * SCAN_TILE + t * SCAN_PER_T;
    int local = 0;
#pragma unroll
    for (int k = 0; k < SCAN_PER_T; ++k) {
        int i = gbase + k;
        if (i < n) local += deg[i];
    }
    s[t] = local;
    __syncthreads();
    for (int off = SCAN_THREADS / 2; off > 0; off >>= 1) {
        if (t < off) s[t] += s[t + off];
        __syncthreads();
    }
    if (t == 0) bsum[blockIdx.x] = s[0];
}

__global__ __launch_bounds__(SCAN_THREADS) void scan_bsums_kernel(int* __restrict__ bsum,
                                                                  int* __restrict__ row_ptr,
                                                                  int nb, int n) {
    __shared__ int s[SCAN_THREADS];
    int t = threadIdx.x;
    s[t] = (t < nb) ? bsum[t] : 0;
    __syncthreads();
    for (int off = 1; off < SCAN_THREADS; off <<= 1) {
        int v = (t >= off) ? s[t - off] : 0;
        __syncthreads();
        s[t] += v;
        __syncthreads();
    }
    if (t < nb) bsum[t] = (t == 0) ? 0 : s[t - 1];   // exclusive prefix
    if (t == 0) row_ptr[n] = s[nb - 1];              // == E
}

__global__ __launch_bounds__(SCAN_THREADS) void tile_apply_kernel(int* __restrict__ deg,
                                                                  const int* __restrict__ bsum,
                                                                  int* __restrict__ row_ptr,
                                                                  float* __restrict__ dinv,
                                                                  int n) {
    __shared__ int s[SCAN_THREADS];
    int t = threadIdx.x;
    int gbase = blockIdx.x * SCAN_TILE + t * SCAN_PER_T;

    int d[SCAN_PER_T];
    int inc[SCAN_PER_T];
    int run = 0;
#pragma unroll
    for (int k = 0; k < SCAN_PER_T; ++k) {
        int i = gbase + k;
        d[k] = (i < n) ? deg[i] : 0;
        run += d[k];
        inc[k] = run;
    }
    s[t] = run;
    __syncthreads();
    for (int off = 1; off < SCAN_THREADS; off <<= 1) {
        int v = (t >= off) ? s[t - off] : 0;
        __syncthreads();
        s[t] += v;
        __syncthreads();
    }
    int base = bsum[blockIdx.x] + ((t == 0) ? 0 : s[t - 1]);
#pragma unroll
    for (int k = 0; k < SCAN_PER_T; ++k) {
        int i = gbase + k;
        if (i < n) {
            int ex = base + inc[k] - d[k];
            row_ptr[i] = ex;
            deg[i] = ex;                            // fill cursor
            dinv[i] = rsqrtf((float)(d[k] + 1));    // +1 = self loop
        }
    }
}

__global__ __launch_bounds__(256) void fill_kernel(const int* __restrict__ src,
                                                   const int* __restrict__ dst,
                                                   int* __restrict__ cursor,
                                                   int* __restrict__ col, int E) {
    int e = blockIdx.x * blockDim.x + threadIdx.x;
    if (e < E) {
        int pos = atomicAdd(&cursor[dst[e]], 1);
        col[pos] = src[e];
    }
}

// Micro-tiled GEMM with single-barrier double-buffer and OUT-slice blocks.
// H'[i, jb0:jb0+OSL] = dinv[i] * (X[i] @ W[:, jb0:jb0+OSL]),
// jb0 = blockIdx.y * OSL. Thread tile TM x TN over a BM x OSL block tile.
// Xs[buf][k][node] stride 132 (conflict-free b128 reads). One barrier per
// k-tile: iter kt writes tile kt+1 into Xs[cur^1] (read next iter), then
// computes from Xs[cur].
template <int IN, int OUT, int OSL, int BM, int TM, int TN>
__global__ __launch_bounds__(256) void gemm_tiled(const float* __restrict__ X,
                                                  const float* __restrict__ W,
                                                  const float* __restrict__ dinv,
                                                  float* __restrict__ H, int n) {
    constexpr int BK = 32;
    constexpr int S = 132;                   // transposed row stride (words)
    constexpr int NTX = OSL / TN;            // threads along the OUT slice
    constexpr int NKT = IN / BK;
    static_assert(NTX * (BM / TM) == 256, "thread mapping");

    __shared__ float Ws[IN * OSL];
    __shared__ float Xs[2][BK * S];

    const int t = threadIdx.x;
    const int jb0 = blockIdx.y * OSL;
    // stage W slice: rows of OSL floats (OSL/4 float4s per row)
    for (int f = t; f < IN * OSL / 4; f += 256) {
        int row = f / (OSL / 4);
        int q = f % (OSL / 4);
        ((float4*)Ws)[f] = *(const float4*)(W + (size_t)row * OUT + jb0 + q * 4);
    }

    const int node0 = blockIdx.x * BM;
    const int tx = t % NTX;
    const int ty = t / NTX;
    const int row0 = ty * TM;
    const int jb = tx * TN;

    const int snd = t >> 3;                  // node row 0..31 (x4 via +32*i)
    const int skq = t & 7;                   // k-quad 0..7

    float acc[TM][TN];
#pragma unroll
    for (int i = 0; i < TM; ++i)
#pragma unroll
        for (int j = 0; j < TN; ++j) acc[i][j] = 0.f;

    float4 stg[4];
    // prologue: tile 0 -> stg -> Xs[0]; tile 1 -> stg
#pragma unroll
    for (int i = 0; i < 4; ++i) {
        int nd = snd + 32 * i;
        stg[i] = make_float4(0.f, 0.f, 0.f, 0.f);
        if (node0 + nd < n)
            stg[i] = *(const float4*)(X + (size_t)(node0 + nd) * IN + skq * 4);
    }
#pragma unroll
    for (int i = 0; i < 4; ++i) {
        int nd = snd + 32 * i;
        float* p = Xs[0] + (skq * 4) * S + nd;
        p[0 * S] = stg[i].x; p[1 * S] = stg[i].y;
        p[2 * S] = stg[i].z; p[3 * S] = stg[i].w;
    }
    if (NKT > 1) {
#pragma unroll
        for (int i = 0; i < 4; ++i) {
            int nd = snd + 32 * i;
            stg[i] = make_float4(0.f, 0.f, 0.f, 0.f);
            if (node0 + nd < n)
                stg[i] = *(const float4*)(X + (size_t)(node0 + nd) * IN + BK + skq * 4);
        }
    }

    int cur = 0;
    for (int kt = 0; kt < NKT; ++kt) {
        __syncthreads();
        // write tile kt+1 into the buffer nobody reads this iteration
        if (kt + 1 < NKT) {
#pragma unroll
            for (int i = 0; i < 4; ++i) {
                int nd = snd + 32 * i;
                float* p = Xs[cur ^ 1] + (skq * 4) * S + nd;
                p[0 * S] = stg[i].x; p[1 * S] = stg[i].y;
                p[2 * S] = stg[i].z; p[3 * S] = stg[i].w;
            }
        }
        // issue tile kt+2 loads
        if (kt + 2 < NKT) {
#pragma unroll
            for (int i = 0; i < 4; ++i) {
                int nd = snd + 32 * i;
                stg[i] = make_float4(0.f, 0.f, 0.f, 0.f);
                if (node0 + nd < n)
                    stg[i] = *(const float4*)(X + (size_t)(node0 + nd) * IN +
                                              (kt + 2) * BK + skq * 4);
            }
        }

        const float* xb = Xs[cur];
        const float* wb = Ws + (size_t)kt * BK * OSL + jb;
#pragma unroll 4
        for (int k = 0; k < BK; ++k) {
            float4 wv = *(const float4*)(wb + (size_t)k * OSL);
            float xv[TM];
#pragma unroll
            for (int i4 = 0; i4 < TM; i4 += 4) {
                float4 xq = *(const float4*)(xb + k * S + row0 + i4);
                xv[i4 + 0] = xq.x; xv[i4 + 1] = xq.y;
                xv[i4 + 2] = xq.z; xv[i4 + 3] = xq.w;
            }
#pragma unroll
            for (int i = 0; i < TM; ++i) {
                acc[i][0] += xv[i] * wv.x;
                acc[i][1] += xv[i] * wv.y;
                acc[i][2] += xv[i] * wv.z;
                acc[i][3] += xv[i] * wv.w;
            }
        }
        cur ^= 1;
    }

#pragma unroll
    for (int i = 0; i < TM; ++i) {
        int node = node0 + row0 + i;
        if (node < n) {
            float di = dinv[node];
            *(float4*)(H + (size_t)node * OUT + jb0 + jb) =
                make_float4(di * acc[i][0], di * acc[i][1],
                            di * acc[i][2], di * acc[i][3]);
        }
    }
}

// Gather aggregation over prescaled H' (= dinv*H):
// OUT[i] = relu(dinv[i] * (Sum_{s in N(i)} H'[s] + H'[i]) + b)
// 4-way edge unroll for gather ILP; inner loop has no dinv access.
template <int F>
__global__ __launch_bounds__(256) void agg_relu_kernel(const int* __restrict__ row_ptr,
                                                       const int* __restrict__ col,
                                                       const float* __restrict__ dinv,
                                                       const float* __restrict__ H,
                                                       const float* __restrict__ b,
                                                       float* __restrict__ OUT, int n) {
    constexpr int TPE = F / 4;
    int t = blockIdx.x * blockDim.x + threadIdx.x;
    int node = t / TPE;
    int c = t % TPE;
    if (node >= n) return;
    int rs = row_ptr[node], re = row_ptr[node + 1];
    float4 acc = make_float4(0.f, 0.f, 0.f, 0.f);
    int e = rs;
    for (; e + 3 < re; e += 4) {
        int s0 = col[e], s1 = col[e + 1], s2 = col[e + 2], s3 = col[e + 3];
        float4 v0 = *(const float4*)(H + (size_t)s0 * F + c * 4);
        float4 v1 = *(const float4*)(H + (size_t)s1 * F + c * 4);
        float4 v2 = *(const float4*)(H + (size_t)s2 * F + c * 4);
        float4 v3 = *(const float4*)(H + (size_t)s3 * F + c * 4);
        acc.x += (v0.x + v1.x) + (v2.x + v3.x);
        acc.y += (v0.y + v1.y) + (v2.y + v3.y);
        acc.z += (v0.z + v1.z) + (v2.z + v3.z);
        acc.w += (v0.w + v1.w) + (v2.w + v3.w);
    }
    for (; e < re; ++e) {
        int s0 = col[e];
        float4 v0 = *(const float4*)(H + (size_t)s0 * F + c * 4);
        acc.x += v0.x; acc.y += v0.y; acc.z += v0.z; acc.w += v0.w;
    }
    float di = dinv[node];
    float4 hs = *(const float4*)(H + (size_t)node * F + c * 4);
    float4 bb = *(const float4*)(b + c * 4);
    float4 r;
    r.x = di * (acc.x + hs.x) + bb.x;
    r.y = di * (acc.y + hs.y) + bb.y;
    r.z = di * (acc.z + hs.z) + bb.z;
    r.w = di * (acc.w + hs.w) + bb.w;
    r.x = r.x > 0.f ? r.x : 0.f;
    r.y = r.y > 0.f ? r.y : 0.f;
    r.z = r.z > 0.f ? r.z : 0.f;
    r.w = r.w > 0.f ? r.w : 0.f;
    *(float4*)(OUT + (size_t)node * F + c * 4) = r;
}

// Layer-2 aggregation (prescaled H2') fused with the classifier head:
// out[i] = relu(dinv[i]*(Sum H2'[s] + H2'[i]) + b2) . Wc + bc
__global__ __launch_bounds__(256) void agg_final_kernel(const int* __restrict__ row_ptr,
                                                        const int* __restrict__ col,
                                                        const float* __restrict__ dinv,
                                                        const float* __restrict__ H,
                                                        const float* __restrict__ b2,
                                                        const float* __restrict__ Wc,
                                                        const float* __restrict__ bc,
                                                        float* __restrict__ out, int n) {
    constexpr int F = 32, TPE = 8;
    int t = blockIdx.x * blockDim.x + threadIdx.x;
    int node = t / TPE;
    int c = t % TPE;
    if (node >= n) return;
    int rs = row_ptr[node], re = row_ptr[node + 1];
    float4 acc = make_float4(0.f, 0.f, 0.f, 0.f);
    int e = rs;
    for (; e + 3 < re; e += 4) {
        int s0 = col[e], s1 = col[e + 1], s2 = col[e + 2], s3 = col[e + 3];
        float4 v0 = *(const float4*)(H + (size_t)s0 * F + c * 4);
        float4 v1 = *(const float4*)(H + (size_t)s1 * F + c * 4);
        float4 v2 = *(const float4*)(H + (size_t)s2 * F + c * 4);
        float4 v3 = *(const float4*)(H + (size_t)s3 * F + c * 4);
        acc.x += (v0.x + v1.x) + (v2.x + v3.x);
        acc.y += (v0.y + v1.y) + (v2.y + v3.y);
        acc.z += (v0.z + v1.z) + (v2.z + v3.z);
        acc.w += (v0.w + v1.w) + (v2.w + v3.w);
    }
    for (; e < re; ++e) {
        int s0 = col[e];
        float4 v0 = *(const float4*)(H + (size_t)s0 * F + c * 4);
        acc.x += v0.x; acc.y += v0.y; acc.z += v0.z; acc.w += v0.w;
    }
    float di = dinv[node];
    float4 hs = *(const float4*)(H + (size_t)node * F + c * 4);
    float4 bb = *(const float4*)(b2 + c * 4);
    float4 wc = *(const float4*)(Wc + c * 4);
    float4 r;
    r.x = di * (acc.x + hs.x) + bb.x;
    r.y = di * (acc.y + hs.y) + bb.y;
    r.z = di * (acc.z + hs.z) + bb.z;
    r.w = di * (acc.w + hs.w) + bb.w;
    float dot = (r.x > 0.f ? r.x : 0.f) * wc.x + (r.y > 0.f ? r.y : 0.f) * wc.y +
                (r.z > 0.f ? r.z : 0.f) * wc.z + (r.w > 0.f ? r.w : 0.f) * wc.w;
    dot += __shfl_xor(dot, 1, 8);
    dot += __shfl_xor(dot, 2, 8);
    dot += __shfl_xor(dot, 4, 8);
    if (c == 0) out[node] = dot + bc[0];
}

extern "C" void kernel_launch(void* const* d_in, const int* in_sizes, int n_in,
                              void* d_out, int out_size, void* d_ws, size_t ws_size,
                              hipStream_t stream) {
    const float* x  = (const float*)d_in[0];
    const int*   ei = (const int*)d_in[1];  // int32 edge_index
    const float* W1 = (const float*)d_in[2];
    const float* b1 = (const float*)d_in[3];
    const float* W2 = (const float*)d_in[4];
    const float* b2 = (const float*)d_in[5];
    const float* Wc = (const float*)d_in[6];
    const float* bc = (const float*)d_in[7];
    float* out = (float*)d_out;

    const int n = in_sizes[0] / 128;   // 100000
    const int E = in_sizes[1] / 2;     // 600000

    const int* src = ei;
    const int* dst = ei + (size_t)E;

    const int nb = (n + SCAN_TILE - 1) / SCAN_TILE;   // 49 blocks (<=256)

    // ws layout (4B elems): dinv[n] | deg/cursor[n] | row_ptr[n+1] | col[E]
    //                       | bsum[256] | bufA[64n] | bufB[64n]
    float* dinv    = (float*)d_ws;
    int*   deg     = (int*)d_ws + n;
    int*   row_ptr = (int*)d_ws + 2 * (size_t)n;
    int*   col     = row_ptr + (n + 1);
    int*   bsum    = col + E;
    float* bufA    = (float*)(bsum + 256);     // h1', then h2'
    float* bufB    = bufA + (size_t)n * 64;    // hr1

    hipMemsetAsync(deg, 0, (size_t)n * 4, stream);
    count_kernel<<<(E + 255) / 256, 256, 0, stream>>>(dst, deg, E);
    tile_reduce_kernel<<<nb, SCAN_THREADS, 0, stream>>>(deg, bsum, n);
    scan_bsums_kernel<<<1, SCAN_THREADS, 0, stream>>>(bsum, row_ptr, nb, n);
    tile_apply_kernel<<<nb, SCAN_THREADS, 0, stream>>>(deg, bsum, row_ptr, dinv, n);
    fill_kernel<<<(E + 255) / 256, 256, 0, stream>>>(src, dst, deg, col, E);

    const int gemm_bx = (n + 127) / 128;   // BM=128 nodes per block

    // Layer 1: OUT=64 split into 2 slices of 32; TM=4, TN=4 (8x32 threads)
    {
        dim3 grid(gemm_bx, 2);
        gemm_tiled<128, 64, 32, 128, 4, 4><<<grid, 256, 0, stream>>>(x, W1, dinv, bufA, n);
    }
    agg_relu_kernel<64><<<(n * 16 + 255) / 256, 256, 0, stream>>>(row_ptr, col, dinv,
                                                                  bufA, b1, bufB, n);
    // Layer 2 + head: OUT=32, single slice; TM=4, TN=4
    {
        dim3 grid(gemm_bx, 1);
        gemm_tiled<64, 32, 32, 128, 4, 4><<<grid, 256, 0, stream>>>(bufB, W2, dinv, bufA, n);
    }
    agg_final_kernel<<<(n * 8 + 255) / 256, 256, 0, stream>>>(row_ptr, col, dinv,
                                                              bufA, b2, Wc, bc, out, n);
}

// Round 17
// 258.446 us; speedup vs baseline: 1.0311x; 1.0311x over previous
//
#include <hip/hip_runtime.h>

// ---------------------------------------------------------------------------
// HabitatGNN: 2-layer GCN (self loops, symmetric norm) + linear head.
// x:[N,128] f32, edge_index:[2,E] int32, W1:[128,64], W2:[64,32], Wc:[32,1].
//
// R5:  atomic scatter = 75% of runtime -> CSR + gather.
// R6:  single-block scan = 51% -> 3-phase device-wide scan.
// R7-R13: gemm 70->39.6us (micro-tile + dbuf + transposed Xs).
// R14: dinv folded into gemm epilogue + agg 4-way unroll (kept).
// R16: OUT-split doubled FETCH (X re-staged per slice) -> 43us. REVERTED.
//      single-barrier pipeline verified correct (kept).
// R17: (a) gemm1 = single-barrier + full OUT (no X replication);
//      (b) gemm2 FUSED into agg_relu: hr1 rows staged in LDS per block,
//      each thread computes 2 cols of h2' = dinv*(hr1@W2). Kills the gemm2
//      dispatch + 51MB hr1 HBM round-trip.
// ---------------------------------------------------------------------------

#define SCAN_THREADS 256
#define SCAN_PER_T   8
#define SCAN_TILE    (SCAN_THREADS * SCAN_PER_T)   // 2048 elements per block

__global__ __launch_bounds__(256) void count_kernel(const int* __restrict__ dst,
                                                    int* __restrict__ deg, int E) {
    int e = blockIdx.x * blockDim.x + threadIdx.x;
    if (e < E) atomicAdd(&deg[dst[e]], 1);
}

__global__ __launch_bounds__(SCAN_THREADS) void tile_reduce_kernel(const int* __restrict__ deg,
                                                                   int* __restrict__ bsum,
                                                                   int n) {
    __shared__ int s[SCAN_THREADS];
    int t = threadIdx.x;
    int gbase = blockIdx.x * SCAN_TILE + t * SCAN_PER_T;
    int local = 0;
#pragma unroll
    for (int k = 0; k < SCAN_PER_T; ++k) {
        int i = gbase + k;
        if (i < n) local += deg[i];
    }
    s[t] = local;
    __syncthreads();
    for (int off = SCAN_THREADS / 2; off > 0; off >>= 1) {
        if (t < off) s[t] += s[t + off];
        __syncthreads();
    }
    if (t == 0) bsum[blockIdx.x] = s[0];
}

__global__ __launch_bounds__(SCAN_THREADS) void scan_bsums_kernel(int* __restrict__ bsum,
                                                                  int* __restrict__ row_ptr,
                                                                  int nb, int n) {
    __shared__ int s[SCAN_THREADS];
    int t = threadIdx.x;
    s[t] = (t < nb) ? bsum[t] : 0;
    __syncthreads();
    for (int off = 1; off < SCAN_THREADS; off <<= 1) {
        int v = (t >= off) ? s[t - off] : 0;
        __syncthreads();
        s[t] += v;
        __syncthreads();
    }
    if (t < nb) bsum[t] = (t == 0) ? 0 : s[t - 1];   // exclusive prefix
    if (t == 0) row_ptr[n] = s[nb - 1];              // == E
}

__global__ __launch_bounds__(SCAN_THREADS) void tile_apply_kernel(int* __restrict__ deg,
                                                                  const int* __restrict__ bsum,
                                                                  int* __restrict__ row_ptr,
                                                                  float* __restrict__ dinv,
                                                                  int n) {
    __shared__ int s[SCAN_THREADS];
    int t = threadIdx.x;
    int gbase = blockIdx.x * SCAN_TILE + t * SCAN_PER_T;

    int d[SCAN_PER_T];
    int inc[SCAN_PER_T];
    int run = 0;
#pragma unroll
    for (int k = 0; k < SCAN_PER_T; ++k) {
        int i = gbase + k;
        d[k] = (i < n) ? deg[i] : 0;
        run += d[k];
        inc[k] = run;
    }
    s[t] = run;
    __syncthreads();
    for (int off = 1; off < SCAN_THREADS; off <<= 1) {
        int v = (t >= off) ? s[t - off] : 0;
        __syncthreads();
        s[t] += v;
        __syncthreads();
    }
    int base = bsum[blockIdx.x] + ((t == 0) ? 0 : s[t - 1]);
#pragma unroll
    for (int k = 0; k < SCAN_PER_T; ++k) {
        int i = gbase + k;
        if (i < n) {
            int ex = base + inc[k] - d[k];
            row_ptr[i] = ex;
            deg[i] = ex;                            // fill cursor
            dinv[i] = rsqrtf((float)(d[k] + 1));    // +1 = self loop
        }
    }
}

__global__ __launch_bounds__(256) void fill_kernel(const int* __restrict__ src,
                                                   const int* __restrict__ dst,
                                                   int* __restrict__ cursor,
                                                   int* __restrict__ col, int E) {
    int e = blockIdx.x * blockDim.x + threadIdx.x;
    if (e < E) {
        int pos = atomicAdd(&cursor[dst[e]], 1);
        col[pos] = src[e];
    }
}

// Micro-tiled GEMM, single barrier per k-tile, full OUT per block (no X
// replication). H'[i] = dinv[i] * (X[i] @ W). Xs[buf][k][node] stride 132.
template <int IN, int OUT, int BM, int TM, int TN>
__global__ __launch_bounds__(256) void gemm_tiled(const float* __restrict__ X,
                                                  const float* __restrict__ W,
                                                  const float* __restrict__ dinv,
                                                  float* __restrict__ H, int n) {
    constexpr int BK = 32;
    constexpr int S = 132;                   // transposed row stride (words)
    constexpr int NTX = OUT / TN;
    constexpr int NKT = IN / BK;
    static_assert(NTX * (BM / TM) == 256, "thread mapping");

    __shared__ float Ws[IN * OUT];
    __shared__ float Xs[2][BK * S];

    const int t = threadIdx.x;
    for (int i = t; i < IN * OUT / 4; i += 256)
        ((float4*)Ws)[i] = ((const float4*)W)[i];

    const int node0 = blockIdx.x * BM;
    const int tx = t % NTX;
    const int ty = t / NTX;
    const int row0 = ty * TM;
    const int jb = tx * TN;

    const int snd = t >> 3;                  // node row 0..31 (x4 via +32*i)
    const int skq = t & 7;                   // k-quad 0..7

    float acc[TM][TN];
#pragma unroll
    for (int i = 0; i < TM; ++i)
#pragma unroll
        for (int j = 0; j < TN; ++j) acc[i][j] = 0.f;

    float4 stg[4];
    // prologue: tile 0 -> stg -> Xs[0]; tile 1 -> stg
#pragma unroll
    for (int i = 0; i < 4; ++i) {
        int nd = snd + 32 * i;
        stg[i] = make_float4(0.f, 0.f, 0.f, 0.f);
        if (node0 + nd < n)
            stg[i] = *(const float4*)(X + (size_t)(node0 + nd) * IN + skq * 4);
    }
#pragma unroll
    for (int i = 0; i < 4; ++i) {
        int nd = snd + 32 * i;
        float* p = Xs[0] + (skq * 4) * S + nd;
        p[0 * S] = stg[i].x; p[1 * S] = stg[i].y;
        p[2 * S] = stg[i].z; p[3 * S] = stg[i].w;
    }
    if (NKT > 1) {
#pragma unroll
        for (int i = 0; i < 4; ++i) {
            int nd = snd + 32 * i;
            stg[i] = make_float4(0.f, 0.f, 0.f, 0.f);
            if (node0 + nd < n)
                stg[i] = *(const float4*)(X + (size_t)(node0 + nd) * IN + BK + skq * 4);
        }
    }

    int cur = 0;
    for (int kt = 0; kt < NKT; ++kt) {
        __syncthreads();
        if (kt + 1 < NKT) {   // write tile kt+1 into the buffer not read now
#pragma unroll
            for (int i = 0; i < 4; ++i) {
                int nd = snd + 32 * i;
                float* p = Xs[cur ^ 1] + (skq * 4) * S + nd;
                p[0 * S] = stg[i].x; p[1 * S] = stg[i].y;
                p[2 * S] = stg[i].z; p[3 * S] = stg[i].w;
            }
        }
        if (kt + 2 < NKT) {   // issue tile kt+2 loads
#pragma unroll
            for (int i = 0; i < 4; ++i) {
                int nd = snd + 32 * i;
                stg[i] = make_float4(0.f, 0.f, 0.f, 0.f);
                if (node0 + nd < n)
                    stg[i] = *(const float4*)(X + (size_t)(node0 + nd) * IN +
                                              (kt + 2) * BK + skq * 4);
            }
        }

        const float* xb = Xs[cur];
        const float* wb = Ws + (size_t)kt * BK * OUT + jb;
#pragma unroll 4
        for (int k = 0; k < BK; ++k) {
            float4 wv = *(const float4*)(wb + (size_t)k * OUT);
            float xv[TM];
#pragma unroll
            for (int i4 = 0; i4 < TM; i4 += 4) {
                float4 xq = *(const float4*)(xb + k * S + row0 + i4);
                xv[i4 + 0] = xq.x; xv[i4 + 1] = xq.y;
                xv[i4 + 2] = xq.z; xv[i4 + 3] = xq.w;
            }
#pragma unroll
            for (int i = 0; i < TM; ++i) {
                acc[i][0] += xv[i] * wv.x;
                acc[i][1] += xv[i] * wv.y;
                acc[i][2] += xv[i] * wv.z;
                acc[i][3] += xv[i] * wv.w;
            }
        }
        cur ^= 1;
    }

#pragma unroll
    for (int i = 0; i < TM; ++i) {
        int node = node0 + row0 + i;
        if (node < n) {
            float di = dinv[node];
            *(float4*)(H + (size_t)node * OUT + jb) =
                make_float4(di * acc[i][0], di * acc[i][1],
                            di * acc[i][2], di * acc[i][3]);
        }
    }
}

// FUSED layer-1 aggregation + layer-2 dense:
//   hr1[i] = relu(dinv[i]*(Sum H1'[s] + H1'[i]) + b1)   (in LDS, per block)
//   H2'[i] = dinv[i] * (hr1[i] @ W2)                    (written to global)
// Block = 16 nodes x 16 threads. H1' is prescaled (= dinv*h1).
__global__ __launch_bounds__(256) void agg_gemm2_kernel(const int* __restrict__ row_ptr,
                                                        const int* __restrict__ col,
                                                        const float* __restrict__ dinv,
                                                        const float* __restrict__ H1,
                                                        const float* __restrict__ b1,
                                                        const float* __restrict__ W2,
                                                        float* __restrict__ H2, int n) {
    constexpr int F = 64, TPE = 16;
    __shared__ float W2s[64 * 32];           // 8 KB
    __shared__ float hr[16][F + 4];          // 4.25 KB, pad 4 vs bank stride

    int t = threadIdx.x;
    for (int i = t; i < 64 * 32 / 4; i += 256)
        ((float4*)W2s)[i] = ((const float4*)W2)[i];

    int ln = t / TPE;                        // local node 0..15
    int c = t % TPE;                         // float4 column 0..15
    int node = blockIdx.x * 16 + ln;
    float di = 0.f;

    if (node < n) {
        int rs = row_ptr[node], re = row_ptr[node + 1];
        float4 acc = make_float4(0.f, 0.f, 0.f, 0.f);
        int e = rs;
        for (; e + 3 < re; e += 4) {
            int s0 = col[e], s1 = col[e + 1], s2 = col[e + 2], s3 = col[e + 3];
            float4 v0 = *(const float4*)(H1 + (size_t)s0 * F + c * 4);
            float4 v1 = *(const float4*)(H1 + (size_t)s1 * F + c * 4);
            float4 v2 = *(const float4*)(H1 + (size_t)s2 * F + c * 4);
            float4 v3 = *(const float4*)(H1 + (size_t)s3 * F + c * 4);
            acc.x += (v0.x + v1.x) + (v2.x + v3.x);
            acc.y += (v0.y + v1.y) + (v2.y + v3.y);
            acc.z += (v0.z + v1.z) + (v2.z + v3.z);
            acc.w += (v0.w + v1.w) + (v2.w + v3.w);
        }
        for (; e < re; ++e) {
            int s0 = col[e];
            float4 v0 = *(const float4*)(H1 + (size_t)s0 * F + c * 4);
            acc.x += v0.x; acc.y += v0.y; acc.z += v0.z; acc.w += v0.w;
        }
        di = dinv[node];
        float4 hs = *(const float4*)(H1 + (size_t)node * F + c * 4);
        float4 bb = *(const float4*)(b1 + c * 4);
        float rx = di * (acc.x + hs.x) + bb.x;
        float ry = di * (acc.y + hs.y) + bb.y;
        float rz = di * (acc.z + hs.z) + bb.z;
        float rw = di * (acc.w + hs.w) + bb.w;
        hr[ln][c * 4 + 0] = rx > 0.f ? rx : 0.f;
        hr[ln][c * 4 + 1] = ry > 0.f ? ry : 0.f;
        hr[ln][c * 4 + 2] = rz > 0.f ? rz : 0.f;
        hr[ln][c * 4 + 3] = rw > 0.f ? rw : 0.f;
    }
    __syncthreads();

    // h2'[node][j], j = 2 columns per thread
    if (node < n) {
        int j = c * 2;
        float s0 = 0.f, s1 = 0.f;
        const float* hrow = hr[ln];
#pragma unroll 8
        for (int k = 0; k < 64; ++k) {
            float h = hrow[k];
            s0 += h * W2s[k * 32 + j];
            s1 += h * W2s[k * 32 + j + 1];
        }
        H2[(size_t)node * 32 + j]     = di * s0;
        H2[(size_t)node * 32 + j + 1] = di * s1;
    }
}

// Layer-2 aggregation (prescaled H2') fused with the classifier head:
// out[i] = relu(dinv[i]*(Sum H2'[s] + H2'[i]) + b2) . Wc + bc
__global__ __launch_bounds__(256) void agg_final_kernel(const int* __restrict__ row_ptr,
                                                        const int* __restrict__ col,
                                                        const float* __restrict__ dinv,
                                                        const float* __restrict__ H,
                                                        const float* __restrict__ b2,
                                                        const float* __restrict__ Wc,
                                                        const float* __restrict__ bc,
                                                        float* __restrict__ out, int n) {
    constexpr int F = 32, TPE = 8;
    int t = blockIdx.x * blockDim.x + threadIdx.x;
    int node = t / TPE;
    int c = t % TPE;
    if (node >= n) return;
    int rs = row_ptr[node], re = row_ptr[node + 1];
    float4 acc = make_float4(0.f, 0.f, 0.f, 0.f);
    int e = rs;
    for (; e + 3 < re; e += 4) {
        int s0 = col[e], s1 = col[e + 1], s2 = col[e + 2], s3 = col[e + 3];
        float4 v0 = *(const float4*)(H + (size_t)s0 * F + c * 4);
        float4 v1 = *(const float4*)(H + (size_t)s1 * F + c * 4);
        float4 v2 = *(const float4*)(H + (size_t)s2 * F + c * 4);
        float4 v3 = *(const float4*)(H + (size_t)s3 * F + c * 4);
        acc.x += (v0.x + v1.x) + (v2.x + v3.x);
        acc.y += (v0.y + v1.y) + (v2.y + v3.y);
        acc.z += (v0.z + v1.z) + (v2.z + v3.z);
        acc.w += (v0.w + v1.w) + (v2.w + v3.w);
    }
    for (; e < re; ++e) {
        int s0 = col[e];
        float4 v0 = *(const float4*)(H + (size_t)s0 * F + c * 4);
        acc.x += v0.x; acc.y += v0.y; acc.z += v0.z; acc.w += v0.w;
    }
    float di = dinv[node];
    float4 hs = *(const float4*)(H + (size_t)node * F + c * 4);
    float4 bb = *(const float4*)(b2 + c * 4);
    float4 wc = *(const float4*)(Wc + c * 4);
    float4 r;
    r.x = di * (acc.x + hs.x) + bb.x;
    r.y = di * (acc.y + hs.y) + bb.y;
    r.z = di * (acc.z + hs.z) + bb.z;
    r.w = di * (acc.w + hs.w) + bb.w;
    float dot = (r.x > 0.f ? r.x : 0.f) * wc.x + (r.y > 0.f ? r.y : 0.f) * wc.y +
                (r.z > 0.f ? r.z : 0.f) * wc.z + (r.w > 0.f ? r.w : 0.f) * wc.w;
    dot += __shfl_xor(dot, 1, 8);
    dot += __shfl_xor(dot, 2, 8);
    dot += __shfl_xor(dot, 4, 8);
    if (c == 0) out[node] = dot + bc[0];
}

extern "C" void kernel_launch(void* const* d_in, const int* in_sizes, int n_in,
                              void* d_out, int out_size, void* d_ws, size_t ws_size,
                              hipStream_t stream) {
    const float* x  = (const float*)d_in[0];
    const int*   ei = (const int*)d_in[1];  // int32 edge_index
    const float* W1 = (const float*)d_in[2];
    const float* b1 = (const float*)d_in[3];
    const float* W2 = (const float*)d_in[4];
    const float* b2 = (const float*)d_in[5];
    const float* Wc = (const float*)d_in[6];
    const float* bc = (const float*)d_in[7];
    float* out = (float*)d_out;

    const int n = in_sizes[0] / 128;   // 100000
    const int E = in_sizes[1] / 2;     // 600000

    const int* src = ei;
    const int* dst = ei + (size_t)E;

    const int nb = (n + SCAN_TILE - 1) / SCAN_TILE;   // 49 blocks (<=256)

    // ws layout (4B elems): dinv[n] | deg/cursor[n] | row_ptr[n+1] | col[E]
    //                       | bsum[256] | bufA[64n] | bufB[64n]
    float* dinv    = (float*)d_ws;
    int*   deg     = (int*)d_ws + n;
    int*   row_ptr = (int*)d_ws + 2 * (size_t)n;
    int*   col     = row_ptr + (n + 1);
    int*   bsum    = col + E;
    float* bufA    = (float*)(bsum + 256);     // h1' (n x 64)
    float* bufB    = bufA + (size_t)n * 64;    // h2' (n x 32)

    hipMemsetAsync(deg, 0, (size_t)n * 4, stream);
    count_kernel<<<(E + 255) / 256, 256, 0, stream>>>(dst, deg, E);
    tile_reduce_kernel<<<nb, SCAN_THREADS, 0, stream>>>(deg, bsum, n);
    scan_bsums_kernel<<<1, SCAN_THREADS, 0, stream>>>(bsum, row_ptr, nb, n);
    tile_apply_kernel<<<nb, SCAN_THREADS, 0, stream>>>(deg, bsum, row_ptr, dinv, n);
    fill_kernel<<<(E + 255) / 256, 256, 0, stream>>>(src, dst, deg, col, E);

    const int gemm_bx = (n + 127) / 128;   // BM=128 nodes per block

    // Layer 1: full OUT=64 per block, TM=8, TN=4
    gemm_tiled<128, 64, 128, 8, 4><<<gemm_bx, 256, 0, stream>>>(x, W1, dinv, bufA, n);

    // Layer-1 aggregation + layer-2 dense, fused (16 nodes per block)
    agg_gemm2_kernel<<<(n + 15) / 16, 256, 0, stream>>>(row_ptr, col, dinv,
                                                        bufA, b1, W2, bufB, n);

    // Layer-2 aggregation + classifier head
    agg_final_kernel<<<(n * 8 + 255) / 256, 256, 0, stream>>>(row_ptr, col, dinv,
                                                              bufB, b2, Wc, bc, out, n);
}